// Round 1
// baseline (1149.320 us; speedup 1.0000x reference)
//
#include <hip/hip_runtime.h>

#define T 8192
#define NCH 128
#define NB 8
#define NS (NB * NCH)   // 1024 series
#define TM1 (T - 1)

// ---------------- Kernel A: per-series fracdiff weights (cumprod scan) ----
__global__ __launch_bounds__(256) void wkern(const float* __restrict__ alpha,
                                             float* __restrict__ w) {
  const int sid = blockIdx.x;                 // sid = b*128 + i
  const float a = fmaxf(alpha[sid], 0.f);     // relu(alpha)
  const int j = threadIdx.x;                  // 0..255, chunk of 32 k's
  __shared__ float sc[256];
  const int k0 = j << 5;
  // chunk product c_j = prod_{u=k0+1..k0+32} (u-1-a)/u
  float c = 1.f;
  #pragma unroll
  for (int s = 1; s <= 32; ++s) {
    const float k = (float)(k0 + s);
    c *= (k - 1.f - a) / k;
  }
  sc[j] = c;
  __syncthreads();
  // Hillis-Steele inclusive scan (product)
  for (int off = 1; off < 256; off <<= 1) {
    const float u = (j >= off) ? sc[j - off] : 1.f;
    const float v = sc[j];
    __syncthreads();
    sc[j] = u * v;
    __syncthreads();
  }
  float p = (j == 0) ? 1.f : sc[j - 1];       // exclusive scan = w[k0]
  float* wg = w + (size_t)sid * T;
  wg[k0] = p;
  for (int s = 1; s < 32; ++s) {
    const float k = (float)(k0 + s);
    p *= (k - 1.f - a) / k;
    wg[k0 + s] = p;
  }
}

// ---------------- Kernel B: transpose X (B,T,n) -> xT (B*n, T) ------------
__global__ __launch_bounds__(256) void tkern(const float* __restrict__ X,
                                             float* __restrict__ xT) {
  __shared__ float tile[32][33];
  const int b = blockIdx.z;
  const int i0 = blockIdx.y << 5;
  const int t0 = blockIdx.x << 5;
  const int tx = threadIdx.x;   // 0..31
  const int ty = threadIdx.y;   // 0..7
  #pragma unroll
  for (int k = 0; k < 4; ++k) {
    const int t = t0 + ty + (k << 3);
    tile[ty + (k << 3)][tx] = X[((size_t)b * T + t) * NCH + i0 + tx];
  }
  __syncthreads();
  #pragma unroll
  for (int k = 0; k < 4; ++k) {
    const int i = i0 + ty + (k << 3);
    xT[((size_t)(b * NCH + i)) * T + t0 + tx] = tile[tx][ty + (k << 3)];
  }
}

// ---------------- Kernel C: causal Toeplitz filter per series -------------
// y[t] = sum_{k=0..t} w[k] * x[t-k].  One block per series.
// x staged in LDS with stride-17 padding (lane stride 16 floats would be a
// 32-way bank conflict; +1 pad per 16 -> bank stride 17, conflict-free).
// Thread j owns two reflected 16-output segments (t0=16j and 8176-16j) so
// per-wave trip counts are ~constant (triangle balanced).
__global__ __launch_bounds__(256) void convk(const float* __restrict__ xT,
                                             const float* __restrict__ wglob,
                                             float* __restrict__ yT) {
  const int sid = blockIdx.x;
  const float* xg = xT + (size_t)sid * T;
  const float* wg = wglob + (size_t)sid * T;
  __shared__ float xs[T + (T >> 4)];          // 8704 floats = 34.8 KB
  for (int t = threadIdx.x; t < T; t += 256) {
    xs[t + (t >> 4)] = xg[t];
  }
  __syncthreads();
  const int j = threadIdx.x;
  #pragma unroll
  for (int seg = 0; seg < 2; ++seg) {
    const int t0 = (seg == 0) ? (j << 4) : (8176 - (j << 4));
    float acc[16];
    #pragma unroll
    for (int r = 0; r < 16; ++r) acc[r] = 0.f;
    const int nfull = t0 >> 4;                // full 16-k tiles
    for (int i = 0; i < nfull; ++i) {
      const int K0 = i << 4;
      const float4 w0 = *(const float4*)(wg + K0);
      const float4 w1 = *(const float4*)(wg + K0 + 4);
      const float4 w2 = *(const float4*)(wg + K0 + 8);
      const float4 w3 = *(const float4*)(wg + K0 + 12);
      const float wv[16] = {w0.x, w0.y, w0.z, w0.w, w1.x, w1.y, w1.z, w1.w,
                            w2.x, w2.y, w2.z, w2.w, w3.x, w3.y, w3.z, w3.w};
      // window x[t0-K0-15 .. t0-K0+15]; base = 16m+1, padded base = 17m+1,
      // element q crosses one pad boundary at q>=15.
      const int base = t0 - K0 - 15;
      const float* xb = xs + base + (base >> 4);
      float xl[31];
      #pragma unroll
      for (int q = 0; q < 31; ++q) xl[q] = xb[q + (q >= 15 ? 1 : 0)];
      #pragma unroll
      for (int d = 0; d < 16; ++d) {
        #pragma unroll
        for (int r = 0; r < 16; ++r) {
          acc[r] += wv[d] * xl[r - d + 15];   // x[t0+r-K0-d]
        }
      }
    }
    // partial (triangular) tile: k in [t0, t0+r]
    #pragma unroll
    for (int r = 0; r < 16; ++r) {
      #pragma unroll
      for (int d = 0; d <= r; ++d) {
        acc[r] += wg[t0 + d] * xs[r - d];     // x[r-d] < 16: pad identity
      }
    }
    float* yo = yT + (size_t)sid * T + t0;
    #pragma unroll
    for (int r4 = 0; r4 < 4; ++r4) {
      *(float4*)(yo + (r4 << 2)) = make_float4(acc[r4 * 4], acc[r4 * 4 + 1],
                                               acc[r4 * 4 + 2], acc[r4 * 4 + 3]);
    }
  }
}

// ---------------- Kernel D: out = Y[:,1:,:] - X[:,:-1,:] @ A^T ------------
__global__ __launch_bounds__(256) void outk(const float* __restrict__ X,
                                            const float* __restrict__ A,
                                            const float* __restrict__ yT,
                                            float* __restrict__ out) {
  const int b = blockIdx.y;
  const int t0 = blockIdx.x << 5;             // 32 t's per block
  __shared__ float Xs[32 * 128];
  const float* Xg = X + ((size_t)b * T + t0) * NCH;
  for (int c = threadIdx.x * 4; c < 32 * 128; c += 1024) {
    *(float4*)(Xs + c) = *(const float4*)(Xg + c);
  }
  __syncthreads();
  const int jj = threadIdx.x & 127;           // output channel
  const int th = threadIdx.x >> 7;            // t half (0/1)
  const float* Ag = A + ((size_t)b * NCH + jj) * NCH;
  float acc[16];
  #pragma unroll
  for (int s = 0; s < 16; ++s) acc[s] = 0.f;
  for (int i4 = 0; i4 < 32; ++i4) {
    const float4 av = *(const float4*)(Ag + (i4 << 2));
    #pragma unroll
    for (int s = 0; s < 16; ++s) {
      const float4 xv = *(const float4*)(Xs + (th * 16 + s) * 128 + (i4 << 2));
      acc[s] += av.x * xv.x + av.y * xv.y + av.z * xv.z + av.w * xv.w;
    }
  }
  const float* yg = yT + (size_t)(b * NCH + jj) * T;
  float* og = out + ((size_t)b * TM1 + t0) * NCH + jj;
  #pragma unroll
  for (int s = 0; s < 16; ++s) {
    const int t = t0 + th * 16 + s;
    if (t < TM1) {
      og[(size_t)(th * 16 + s) * NCH] = yg[t + 1] - acc[s];
    }
  }
}

extern "C" void kernel_launch(void* const* d_in, const int* in_sizes, int n_in,
                              void* d_out, int out_size, void* d_ws, size_t ws_size,
                              hipStream_t stream) {
  const float* X     = (const float*)d_in[0];   // (8, 8192, 128)
  const float* alpha = (const float*)d_in[1];   // (8, 128)
  const float* A     = (const float*)d_in[2];   // (8, 128, 128)
  float* out = (float*)d_out;                   // (8, 8191, 128)
  char* ws = (char*)d_ws;
  float* w  = (float*)ws;                               // 32 MB weights
  float* xT = (float*)(ws + ((size_t)32 << 20));        // 32 MB X transposed
  float* yT = (float*)(ws + ((size_t)64 << 20));        // 32 MB Y transposed

  hipLaunchKernelGGL(wkern, dim3(NS), dim3(256), 0, stream, alpha, w);
  hipLaunchKernelGGL(tkern, dim3(T / 32, NCH / 32, NB), dim3(32, 8), 0, stream, X, xT);
  hipLaunchKernelGGL(convk, dim3(NS), dim3(256), 0, stream, xT, w, yT);
  hipLaunchKernelGGL(outk, dim3((TM1 + 31) / 32, NB), dim3(256), 0, stream, X, A, yT, out);
}

// Round 2
// 365.163 us; speedup vs baseline: 3.1474x; 3.1474x over previous
//
#include <hip/hip_runtime.h>

#define T 8192
#define NCH 128
#define NB 8
#define NS (NB * NCH)   // 1024 series
#define TM1 (T - 1)

typedef __bf16 v8bf __attribute__((ext_vector_type(8)));
typedef float v16f __attribute__((ext_vector_type(16)));

#define WREV_LEN 8448                 // per-copy per-series length (elems)
#define WREV_COPY_STRIDE ((size_t)NS * WREV_LEN)

__device__ __forceinline__ ushort f32_to_bf16(float f) {
  union { float f; uint u; } v; v.f = f;
  uint r = (v.u + 0x7FFFu + ((v.u >> 16) & 1u)) >> 16;
  return (ushort)r;
}

// ---------------- Kernel A: weights cumprod -> reversed bf16 (2 parity copies)
// wrev[z] = wpad[8319 - z]  (wpad zero outside [0,8191])
// copy a (a in {0,1}): copy_a[c] = wrev[c + a]
__global__ __launch_bounds__(256) void wkern(const float* __restrict__ alpha,
                                             ushort* __restrict__ wr2) {
  const int sid = blockIdx.x;
  const float a = fmaxf(alpha[sid], 0.f);
  const int j = threadIdx.x;
  __shared__ float sc[256];
  const int k0 = j << 5;
  float c = 1.f;
  #pragma unroll
  for (int s = 1; s <= 32; ++s) {
    const float k = (float)(k0 + s);
    c *= (k - 1.f - a) / k;
  }
  sc[j] = c;
  __syncthreads();
  for (int off = 1; off < 256; off <<= 1) {
    const float u = (j >= off) ? sc[j - off] : 1.f;
    const float v = sc[j];
    __syncthreads();
    sc[j] = u * v;
    __syncthreads();
  }
  float p = (j == 0) ? 1.f : sc[j - 1];
  ushort* c0p = wr2 + (size_t)sid * WREV_LEN;
  ushort* c1p = wr2 + WREV_COPY_STRIDE + (size_t)sid * WREV_LEN;
  // zero pads (disjoint from value ranges)
  for (int z = j; z < 128; z += 256) c0p[z] = 0;
  for (int z = 8320 + j; z < WREV_LEN; z += 256) c0p[z] = 0;
  for (int z = j; z < 127; z += 256) c1p[z] = 0;
  for (int z = 8319 + j; z < WREV_LEN; z += 256) c1p[z] = 0;
  // values: copy0[8319-k] = w[k]; copy1[8318-k] = w[k]
  {
    ushort h = f32_to_bf16(p);
    c0p[8319 - k0] = h;
    c1p[8318 - k0] = h;
  }
  for (int s = 1; s < 32; ++s) {
    const float k = (float)(k0 + s);
    p *= (k - 1.f - a) / k;
    ushort h = f32_to_bf16(p);
    c0p[8319 - (k0 + s)] = h;
    c1p[8318 - (k0 + s)] = h;
  }
}

// ---------------- Kernel B: transpose X (B,T,n) fp32 -> xT (B*n, T) bf16 ---
__global__ __launch_bounds__(256) void tkern(const float* __restrict__ X,
                                             ushort* __restrict__ xT) {
  __shared__ float tile[32][33];
  const int b = blockIdx.z;
  const int i0 = blockIdx.y << 5;
  const int t0 = blockIdx.x << 5;
  const int tx = threadIdx.x;   // 0..31
  const int ty = threadIdx.y;   // 0..7
  #pragma unroll
  for (int k = 0; k < 4; ++k) {
    const int t = t0 + ty + (k << 3);
    tile[ty + (k << 3)][tx] = X[((size_t)b * T + t) * NCH + i0 + tx];
  }
  __syncthreads();
  #pragma unroll
  for (int k = 0; k < 4; ++k) {
    const int i = i0 + ty + (k << 3);
    xT[((size_t)(b * NCH + i)) * T + t0 + tx] = f32_to_bf16(tile[tx][ty + (k << 3)]);
  }
}

// ---------------- Kernel C: causal Toeplitz filter via MFMA -----------------
// One block per series, 4 waves. t = 64Q + m; D[m'][n] (32x32) per (coltile c,
// row-tile rt). A = w-Toeplitz from global parity copies, B = x-Hankel from
// LDS (bf16, pad-4-dwords-per-32 layout, left zero pad 2048 elems).
// Waves interleave 8-step i-chunks; partial D reduced through LDS at end.
__global__ __launch_bounds__(256, 2) void convk(const ushort* __restrict__ wr2,
                                                const ushort* __restrict__ xT,
                                                float* __restrict__ yT) {
  const int sid = blockIdx.x;
  const int tid = threadIdx.x;
  const int wave = tid >> 6;
  const int lane = tid & 63;
  const int ln31 = lane & 31;
  const int q = lane >> 5;

  __shared__ uint arena[5760];   // 23 KB: x-stage (main) / reduce zones (epilogue)

  // zero left pad: x elems [0,2048) -> dwords s in [0,1024) -> p in [0,1152)
  for (int p = tid; p < 1152; p += 256) arena[p] = 0;
  // stage x (8192 bf16 = 4096 dwords), padded layout p = s + 4*(s>>5)
  {
    const uint* xg = (const uint*)xT + (size_t)sid * (T / 2);
    for (int d4 = tid * 4; d4 < T / 2; d4 += 1024) {
      uint4 v = *(const uint4*)(xg + d4);
      int s = 1024 + d4;
      int p = s + 4 * (s >> 5);
      *(uint4*)(arena + p) = v;
    }
  }
  __syncthreads();

  v16f acc[4][2];
  #pragma unroll
  for (int c = 0; c < 4; ++c)
    #pragma unroll
    for (int rt = 0; rt < 2; ++rt)
      #pragma unroll
      for (int e = 0; e < 16; ++e) acc[c][rt][e] = 0.f;

  // per-lane parity-fixed A pointer (s parity independent of i: 16i even)
  const int s0_par = (8303 - ln31 + 8 * q) & 1;   // parity of s0
  const uint* wu = (const uint*)(wr2 + (s0_par ? WREV_COPY_STRIDE : 0) +
                                 (size_t)sid * WREV_LEN);

  // i in [-4, 516) as 65 chunks of 8; wave w takes chunks K ≡ w (mod 4)
  for (int K = wave; K < 65; K += 4) {
    const int ibase = -4 + K * 8;
    // A dword base at ii=0, rt=0: dw = (s0 - parity)/2, s0 = Zi - ln31 + 8q
    const int s0 = 8303 - 16 * ibase - ln31 + 8 * q;
    const int dw0 = (s0 - s0_par) >> 1;
    // B dword base (c=0, ii=0): s = 1024 + 32*ln31 - 8*(ibase+1) + 4q
    const int sb0 = 1024 + 32 * ln31 - 8 * (ibase + 1) + 4 * q;
    #pragma unroll
    for (int ii = 0; ii < 8; ++ii) {
      const int i = ibase + ii;
      const int dw = dw0 - 8 * ii;
      uint4 av0, av1;
      av0.x = wu[dw];      av0.y = wu[dw + 1];  av0.z = wu[dw + 2];  av0.w = wu[dw + 3];
      av1.x = wu[dw - 16]; av1.y = wu[dw - 15]; av1.z = wu[dw - 14]; av1.w = wu[dw - 13];
      const v8bf A0 = __builtin_bit_cast(v8bf, av0);
      const v8bf A1 = __builtin_bit_cast(v8bf, av1);
      const int sb = sb0 - 8 * ii;
      const int pb = sb + 4 * (sb >> 5);      // c-offset separable: +1152*c
      #pragma unroll
      for (int c = 0; c < 4; ++c) {
        if (i < 128 * (c + 1)) {
          uint4 bv = *(const uint4*)(arena + pb + 1152 * c);
          const v8bf Bf = __builtin_bit_cast(v8bf, bv);
          acc[c][0] = __builtin_amdgcn_mfma_f32_32x32x16_bf16(A0, Bf, acc[c][0], 0, 0, 0);
          acc[c][1] = __builtin_amdgcn_mfma_f32_32x32x16_bf16(A1, Bf, acc[c][1], 0, 0, 0);
        }
      }
    }
  }

  // ---- cross-wave reduction of partial D tiles through LDS ----
  // zone layout per wave: 32 cols x 36-stride rows (float), zone w at w*1152
  float* const zbase = (float*)arena;
  const int rowq = 4 * q;
  #pragma unroll
  for (int c = 0; c < 4; ++c) {
    #pragma unroll
    for (int rt = 0; rt < 2; ++rt) {
      __syncthreads();
      float* zone = zbase + wave * 1152;
      #pragma unroll
      for (int g = 0; g < 4; ++g) {
        float4 v = make_float4(acc[c][rt][4 * g], acc[c][rt][4 * g + 1],
                               acc[c][rt][4 * g + 2], acc[c][rt][4 * g + 3]);
        *(float4*)(zone + ln31 * 36 + 8 * g + rowq) = v;   // rows 8g+4q+0..3
      }
      __syncthreads();
      const int n2 = tid & 31, rg = tid >> 5;   // rows 4rg..4rg+3
      const int zi = n2 * 36 + 4 * rg;
      float4 s0 = *(const float4*)(zbase + 0 * 1152 + zi);
      float4 s1 = *(const float4*)(zbase + 1 * 1152 + zi);
      float4 s2 = *(const float4*)(zbase + 2 * 1152 + zi);
      float4 s3 = *(const float4*)(zbase + 3 * 1152 + zi);
      float4 s;
      s.x = s0.x + s1.x + s2.x + s3.x;
      s.y = s0.y + s1.y + s2.y + s3.y;
      s.z = s0.z + s1.z + s2.z + s3.z;
      s.w = s0.w + s1.w + s2.w + s3.w;
      *(float4*)(yT + (size_t)sid * T + 2048 * c + 64 * n2 + 32 * rt + 4 * rg) = s;
    }
  }
}

// ---------------- Kernel D: out = Y[:,1:,:] - X[:,:-1,:] @ A^T ------------
__global__ __launch_bounds__(256) void outk(const float* __restrict__ X,
                                            const float* __restrict__ A,
                                            const float* __restrict__ yT,
                                            float* __restrict__ out) {
  const int b = blockIdx.y;
  const int t0 = blockIdx.x << 5;             // 32 t's per block
  __shared__ float Xs[32 * 128];
  const float* Xg = X + ((size_t)b * T + t0) * NCH;
  for (int c = threadIdx.x * 4; c < 32 * 128; c += 1024) {
    *(float4*)(Xs + c) = *(const float4*)(Xg + c);
  }
  __syncthreads();
  const int jj = threadIdx.x & 127;           // output channel
  const int th = threadIdx.x >> 7;            // t half (0/1)
  const float* Ag = A + ((size_t)b * NCH + jj) * NCH;
  float acc[16];
  #pragma unroll
  for (int s = 0; s < 16; ++s) acc[s] = 0.f;
  for (int i4 = 0; i4 < 32; ++i4) {
    const float4 av = *(const float4*)(Ag + (i4 << 2));
    #pragma unroll
    for (int s = 0; s < 16; ++s) {
      const float4 xv = *(const float4*)(Xs + (th * 16 + s) * 128 + (i4 << 2));
      acc[s] += av.x * xv.x + av.y * xv.y + av.z * xv.z + av.w * xv.w;
    }
  }
  const float* yg = yT + (size_t)(b * NCH + jj) * T;
  float* og = out + ((size_t)b * TM1 + t0) * NCH + jj;
  #pragma unroll
  for (int s = 0; s < 16; ++s) {
    const int t = t0 + th * 16 + s;
    if (t < TM1) {
      og[(size_t)(th * 16 + s) * NCH] = yg[t + 1] - acc[s];
    }
  }
}

extern "C" void kernel_launch(void* const* d_in, const int* in_sizes, int n_in,
                              void* d_out, int out_size, void* d_ws, size_t ws_size,
                              hipStream_t stream) {
  const float* X     = (const float*)d_in[0];   // (8, 8192, 128)
  const float* alpha = (const float*)d_in[1];   // (8, 128)
  const float* A     = (const float*)d_in[2];   // (8, 128, 128)
  float* out = (float*)d_out;                   // (8, 8191, 128)
  char* ws = (char*)d_ws;

  // ws layout (bytes):
  //   wrev2 : 2 copies * 1024 series * 8448 elems * 2B = 34,603,008
  //   xT    : 1024 * 8192 * 2B  = 16,777,216   (bf16, series-major)
  //   yT    : 1024 * 8192 * 4B  = 33,554,432   (fp32, series-major)
  ushort* wr2 = (ushort*)ws;
  ushort* xT  = (ushort*)(ws + 34603008);
  float*  yT  = (float*)(ws + 34603008 + 16777216);

  hipLaunchKernelGGL(wkern, dim3(NS), dim3(256), 0, stream, alpha, wr2);
  hipLaunchKernelGGL(tkern, dim3(T / 32, NCH / 32, NB), dim3(32, 8), 0, stream, X, xT);
  hipLaunchKernelGGL(convk, dim3(NS), dim3(256), 0, stream, wr2, xT, yT);
  hipLaunchKernelGGL(outk, dim3((TM1 + 31) / 32, NB), dim3(256), 0, stream, X, A, yT, out);
}

// Round 3
// 303.858 us; speedup vs baseline: 3.7824x; 1.2018x over previous
//
#include <hip/hip_runtime.h>

#define T 8192
#define NCH 128
#define NB 8
#define NS (NB * NCH)   // 1024 series
#define TM1 (T - 1)

typedef __bf16 v8bf __attribute__((ext_vector_type(8)));
typedef float v16f __attribute__((ext_vector_type(16)));

#define WREV_LEN 8448                 // per-copy per-series length (elems)
#define WREV_COPY_STRIDE ((size_t)NS * WREV_LEN)

__device__ __forceinline__ uint bf_bits(float f) {
  union { float f; uint u; } v; v.f = f;
  return (v.u + 0x7FFFu + ((v.u >> 16) & 1u)) >> 16;
}

// w value (bf16 bits) at index k, from stride-33-padded LDS; 0 outside range
__device__ __forceinline__ uint wbits(const float* wsh, int k) {
  if ((unsigned)k > 8191u) return 0u;
  return bf_bits(wsh[k + (k >> 5)]);
}

// ---------------- Kernel A: weights cumprod -> reversed bf16 (2 parity copies)
// wrev[z] = wpad[8319 - z] (wpad zero outside [0,8191]); copy_a[z] = wrev[z+a].
// w computed into padded LDS, then both copies emitted as coalesced uint stores.
__global__ __launch_bounds__(256) void wkern(const float* __restrict__ alpha,
                                             ushort* __restrict__ wr2) {
  const int sid = blockIdx.x;
  const float a = fmaxf(alpha[sid], 0.f);
  const int j = threadIdx.x;
  __shared__ float sc[256];
  __shared__ float wsh[8448];          // idx k + (k>>5): stride-33, conflict-free
  const int k0 = j << 5;
  float c = 1.f;
  #pragma unroll
  for (int s = 1; s <= 32; ++s) {
    const float k = (float)(k0 + s);
    c *= (k - 1.f - a) / k;
  }
  sc[j] = c;
  __syncthreads();
  for (int off = 1; off < 256; off <<= 1) {
    const float u = (j >= off) ? sc[j - off] : 1.f;
    const float v = sc[j];
    __syncthreads();
    sc[j] = u * v;
    __syncthreads();
  }
  float p = (j == 0) ? 1.f : sc[j - 1];
  wsh[k0 + j] = p;                     // (k0 + s) + ((k0+s)>>5) = k0 + s + j
  for (int s = 1; s < 32; ++s) {
    const float k = (float)(k0 + s);
    p *= (k - 1.f - a) / k;
    wsh[k0 + s + j] = p;
  }
  __syncthreads();
  uint* c0u = (uint*)(wr2 + (size_t)sid * WREV_LEN);
  uint* c1u = (uint*)(wr2 + WREV_COPY_STRIDE + (size_t)sid * WREV_LEN);
  for (int d = j; d < WREV_LEN / 2; d += 256) {
    const int z = 2 * d;
    const uint a0 = wbits(wsh, 8319 - z);
    const uint a1 = wbits(wsh, 8318 - z);   // shared between copies
    const uint a2 = wbits(wsh, 8317 - z);
    c0u[d] = a0 | (a1 << 16);
    c1u[d] = a1 | (a2 << 16);
  }
}

// ---------------- Kernel B: transpose X (B,T,n) fp32 -> xT (B*n, T) bf16 ---
__global__ __launch_bounds__(256) void tkern(const float* __restrict__ X,
                                             ushort* __restrict__ xT) {
  __shared__ float tile[32][33];
  const int b = blockIdx.z;
  const int i0 = blockIdx.y << 5;
  const int t0 = blockIdx.x << 5;
  const int tx = threadIdx.x;   // 0..31
  const int ty = threadIdx.y;   // 0..7
  #pragma unroll
  for (int k = 0; k < 4; ++k) {
    const int t = t0 + ty + (k << 3);
    tile[ty + (k << 3)][tx] = X[((size_t)b * T + t) * NCH + i0 + tx];
  }
  __syncthreads();
  #pragma unroll
  for (int k = 0; k < 4; ++k) {
    const int i = i0 + ty + (k << 3);
    xT[((size_t)(b * NCH + i)) * T + t0 + tx] =
        (ushort)bf_bits(tile[tx][ty + (k << 3)]);
  }
}

// ---------------- Kernel C: causal Toeplitz filter via MFMA -----------------
// One block per series, 4 waves. A = w-Toeplitz (global parity copies),
// B = x-Hankel from LDS. LDS layout: 16B chunk u stored at physical chunk
// phi(u) = (u&7)*160 + (u>>3) -> B-reads (lane chunk stride 8) become
// physically CONTIGUOUS per 32-lane half => conflict-free ds_read_b128.
__global__ __launch_bounds__(256, 2) void convk(const ushort* __restrict__ wr2,
                                                const ushort* __restrict__ xT,
                                                float* __restrict__ yT) {
  const int sid = blockIdx.x;
  const int tid = threadIdx.x;
  const int wave = tid >> 6;
  const int lane = tid & 63;
  const int ln31 = lane & 31;
  const int q = lane >> 5;

  __shared__ uint4 arena16[1280];      // 20 KB; x-stage (main) / reduce zones

  // zero left pad: chunks u in [0,256)  (raw x elems [0,2048))
  {
    const int u = tid;                 // exactly one iteration
    arena16[((u & 7) * 160) + (u >> 3)] = make_uint4(0, 0, 0, 0);
  }
  // stage x: data chunk u = 256 + u0, u0 in [0,1024)
  {
    const uint4* xg16 = (const uint4*)(xT + (size_t)sid * T);
    for (int u0 = tid; u0 < 1024; u0 += 256) {
      const int u = u0 + 256;
      arena16[((u & 7) * 160) + (u >> 3)] = xg16[u0];
    }
  }
  __syncthreads();

  v16f acc[4][2];
  #pragma unroll
  for (int cc = 0; cc < 4; ++cc)
    #pragma unroll
    for (int rt = 0; rt < 2; ++rt)
      #pragma unroll
      for (int e = 0; e < 16; ++e) acc[cc][rt][e] = 0.f;

  // per-lane parity-fixed A pointer (s0 parity independent of i)
  const int s0_par = (8303 - ln31 + 8 * q) & 1;
  const uint* wu = (const uint*)(wr2 + (s0_par ? WREV_COPY_STRIDE : 0) +
                                 (size_t)sid * WREV_LEN);

  // i in [-4, 516) as 65 chunks of 8; wave w takes chunks K ≡ w (mod 4)
  for (int K = wave; K < 65; K += 4) {
    const int ibase = -4 + K * 8;
    const int s0 = 8303 - 16 * ibase - ln31 + 8 * q;
    const int dw0 = (s0 - s0_par) >> 1;
    #pragma unroll
    for (int ii = 0; ii < 8; ++ii) {
      const int i = ibase + ii;
      const int dw = dw0 - 8 * ii;
      uint4 av0, av1;
      av0.x = wu[dw];      av0.y = wu[dw + 1];  av0.z = wu[dw + 2];  av0.w = wu[dw + 3];
      av1.x = wu[dw - 16]; av1.y = wu[dw - 15]; av1.z = wu[dw - 14]; av1.w = wu[dw - 13];
      const v8bf A0 = __builtin_bit_cast(v8bf, av0);
      const v8bf A1 = __builtin_bit_cast(v8bf, av1);
      // B physical chunk: phi = ln31 + G(q) + 32c; G uniform per (q,i)
      const int m2 = -2 * (i + 1);
      const int u70 = m2 & 7;
      const int u71 = (m2 + 1) & 7;
      const int G0 = u70 * 160 + 32 + ((m2 - u70) >> 3);
      const int G1 = u71 * 160 + 32 + ((m2 + 1 - u71) >> 3);
      const int phi = ln31 + (q ? G1 : G0);
      #pragma unroll
      for (int cc = 0; cc < 4; ++cc) {
        if (i < 128 * (cc + 1)) {
          const uint4 bv = arena16[phi + 32 * cc];
          const v8bf Bf = __builtin_bit_cast(v8bf, bv);
          acc[cc][0] = __builtin_amdgcn_mfma_f32_32x32x16_bf16(A0, Bf, acc[cc][0], 0, 0, 0);
          acc[cc][1] = __builtin_amdgcn_mfma_f32_32x32x16_bf16(A1, Bf, acc[cc][1], 0, 0, 0);
        }
      }
    }
  }

  // ---- cross-wave reduction of partial D tiles through LDS ----
  float* const zbase = (float*)arena16;
  const int rowq = 4 * q;
  #pragma unroll
  for (int cc = 0; cc < 4; ++cc) {
    #pragma unroll
    for (int rt = 0; rt < 2; ++rt) {
      __syncthreads();
      float* zone = zbase + wave * 1152;
      #pragma unroll
      for (int g = 0; g < 4; ++g) {
        float4 v = make_float4(acc[cc][rt][4 * g], acc[cc][rt][4 * g + 1],
                               acc[cc][rt][4 * g + 2], acc[cc][rt][4 * g + 3]);
        *(float4*)(zone + ln31 * 36 + 8 * g + rowq) = v;
      }
      __syncthreads();
      const int n2 = tid & 31, rg = tid >> 5;
      const int zi = n2 * 36 + 4 * rg;
      float4 s0 = *(const float4*)(zbase + 0 * 1152 + zi);
      float4 s1 = *(const float4*)(zbase + 1 * 1152 + zi);
      float4 s2 = *(const float4*)(zbase + 2 * 1152 + zi);
      float4 s3 = *(const float4*)(zbase + 3 * 1152 + zi);
      float4 s;
      s.x = s0.x + s1.x + s2.x + s3.x;
      s.y = s0.y + s1.y + s2.y + s3.y;
      s.z = s0.z + s1.z + s2.z + s3.z;
      s.w = s0.w + s1.w + s2.w + s3.w;
      *(float4*)(yT + (size_t)sid * T + 2048 * cc + 64 * n2 + 32 * rt + 4 * rg) = s;
    }
  }
}

// ---------------- Kernel D: out = Y[:,1:,:] - X[:,:-1,:] @ A^T ------------
__global__ __launch_bounds__(256) void outk(const float* __restrict__ X,
                                            const float* __restrict__ A,
                                            const float* __restrict__ yT,
                                            float* __restrict__ out) {
  const int b = blockIdx.y;
  const int t0 = blockIdx.x << 5;             // 32 t's per block
  __shared__ float Xs[32 * 128];
  const float* Xg = X + ((size_t)b * T + t0) * NCH;
  for (int c = threadIdx.x * 4; c < 32 * 128; c += 1024) {
    *(float4*)(Xs + c) = *(const float4*)(Xg + c);
  }
  __syncthreads();
  const int jj = threadIdx.x & 127;           // output channel
  const int th = threadIdx.x >> 7;            // t half (0/1)
  const float* Ag = A + ((size_t)b * NCH + jj) * NCH;
  float acc[16];
  #pragma unroll
  for (int s = 0; s < 16; ++s) acc[s] = 0.f;
  for (int i4 = 0; i4 < 32; ++i4) {
    const float4 av = *(const float4*)(Ag + (i4 << 2));
    #pragma unroll
    for (int s = 0; s < 16; ++s) {
      const float4 xv = *(const float4*)(Xs + (th * 16 + s) * 128 + (i4 << 2));
      acc[s] += av.x * xv.x + av.y * xv.y + av.z * xv.z + av.w * xv.w;
    }
  }
  const float* yg = yT + (size_t)(b * NCH + jj) * T;
  float* og = out + ((size_t)b * TM1 + t0) * NCH + jj;
  #pragma unroll
  for (int s = 0; s < 16; ++s) {
    const int t = t0 + th * 16 + s;
    if (t < TM1) {
      og[(size_t)(th * 16 + s) * NCH] = yg[t + 1] - acc[s];
    }
  }
}

extern "C" void kernel_launch(void* const* d_in, const int* in_sizes, int n_in,
                              void* d_out, int out_size, void* d_ws, size_t ws_size,
                              hipStream_t stream) {
  const float* X     = (const float*)d_in[0];   // (8, 8192, 128)
  const float* alpha = (const float*)d_in[1];   // (8, 128)
  const float* A     = (const float*)d_in[2];   // (8, 128, 128)
  float* out = (float*)d_out;                   // (8, 8191, 128)
  char* ws = (char*)d_ws;

  // ws layout (bytes):
  //   wrev2 : 2 copies * 1024 series * 8448 elems * 2B = 34,603,008
  //   xT    : 1024 * 8192 * 2B  = 16,777,216   (bf16, series-major)
  //   yT    : 1024 * 8192 * 4B  = 33,554,432   (fp32, series-major)
  ushort* wr2 = (ushort*)ws;
  ushort* xT  = (ushort*)(ws + 34603008);
  float*  yT  = (float*)(ws + 34603008 + 16777216);

  hipLaunchKernelGGL(wkern, dim3(NS), dim3(256), 0, stream, alpha, wr2);
  hipLaunchKernelGGL(tkern, dim3(T / 32, NCH / 32, NB), dim3(32, 8), 0, stream, X, xT);
  hipLaunchKernelGGL(convk, dim3(NS), dim3(256), 0, stream, wr2, xT, yT);
  hipLaunchKernelGGL(outk, dim3((TM1 + 31) / 32, NB), dim3(256), 0, stream, X, A, yT, out);
}

// Round 4
// 201.198 us; speedup vs baseline: 5.7124x; 1.5102x over previous
//
#include <hip/hip_runtime.h>

#define T 8192
#define NCH 128
#define NB 8
#define NS (NB * NCH)   // 1024 series
#define TM1 (T - 1)

typedef __bf16 v8bf __attribute__((ext_vector_type(8)));
typedef float v16f __attribute__((ext_vector_type(16)));

#define WREV_LEN 8448                 // per-copy per-series length (elems)
#define WREV_COPY_STRIDE ((size_t)NS * WREV_LEN)

// 16B vector load from a 4B-aligned address (gfx950 unaligned global access)
struct __attribute__((packed, aligned(4))) U16 { uint4 v; };
struct __attribute__((packed, aligned(4))) F16V { float4 v; };

__device__ __forceinline__ uint bf_bits(float f) {
  union { float f; uint u; } v; v.f = f;
  return (v.u + 0x7FFFu + ((v.u >> 16) & 1u)) >> 16;
}

__device__ __forceinline__ uint wbits(const float* wsh, int k) {
  if ((unsigned)k > 8191u) return 0u;
  return bf_bits(wsh[k + (k >> 5)]);
}

// ---------------- Kernel A: weights cumprod -> reversed bf16 (2 parity copies)
__global__ __launch_bounds__(256) void wkern(const float* __restrict__ alpha,
                                             ushort* __restrict__ wr2) {
  const int sid = blockIdx.x;
  const float a = fmaxf(alpha[sid], 0.f);
  const int j = threadIdx.x;
  __shared__ float sc[256];
  __shared__ float wsh[8448];          // idx k + (k>>5): stride-33, conflict-free
  const int k0 = j << 5;
  float c = 1.f;
  #pragma unroll
  for (int s = 1; s <= 32; ++s) {
    const float k = (float)(k0 + s);
    c *= (k - 1.f - a) / k;
  }
  sc[j] = c;
  __syncthreads();
  for (int off = 1; off < 256; off <<= 1) {
    const float u = (j >= off) ? sc[j - off] : 1.f;
    const float v = sc[j];
    __syncthreads();
    sc[j] = u * v;
    __syncthreads();
  }
  float p = (j == 0) ? 1.f : sc[j - 1];
  wsh[k0 + j] = p;
  for (int s = 1; s < 32; ++s) {
    const float k = (float)(k0 + s);
    p *= (k - 1.f - a) / k;
    wsh[k0 + s + j] = p;
  }
  __syncthreads();
  uint* c0u = (uint*)(wr2 + (size_t)sid * WREV_LEN);
  uint* c1u = (uint*)(wr2 + WREV_COPY_STRIDE + (size_t)sid * WREV_LEN);
  for (int d = j; d < WREV_LEN / 2; d += 256) {
    const int z = 2 * d;
    const uint a0 = wbits(wsh, 8319 - z);
    const uint a1 = wbits(wsh, 8318 - z);
    const uint a2 = wbits(wsh, 8317 - z);
    c0u[d] = a0 | (a1 << 16);
    c1u[d] = a1 | (a2 << 16);
  }
}

// ---------------- Kernel B: transpose X (B,T,n) fp32 -> xT (B*n, T) bf16 ---
__global__ __launch_bounds__(256) void tkern(const float* __restrict__ X,
                                             ushort* __restrict__ xT) {
  __shared__ float tile[32][33];
  const int b = blockIdx.z;
  const int i0 = blockIdx.y << 5;
  const int t0 = blockIdx.x << 5;
  const int tx = threadIdx.x;
  const int ty = threadIdx.y;
  #pragma unroll
  for (int k = 0; k < 4; ++k) {
    const int t = t0 + ty + (k << 3);
    tile[ty + (k << 3)][tx] = X[((size_t)b * T + t) * NCH + i0 + tx];
  }
  __syncthreads();
  #pragma unroll
  for (int k = 0; k < 4; ++k) {
    const int i = i0 + ty + (k << 3);
    xT[((size_t)(b * NCH + i)) * T + t0 + tx] =
        (ushort)bf_bits(tile[tx][ty + (k << 3)]);
  }
}

// ---------------- Kernel C: causal Toeplitz filter via MFMA -----------------
// A-frags: ONE unaligned global_load_dwordx4 each (dw mod 4 lane-constant),
// 10-frag ring with av1(ii) = av0(ii+2) reuse -> 10 VMEM per 8-i chunk.
__global__ __launch_bounds__(256, 2) void convk(const ushort* __restrict__ wr2,
                                                const ushort* __restrict__ xT,
                                                float* __restrict__ yT) {
  const int sid = blockIdx.x;
  const int tid = threadIdx.x;
  const int wave = tid >> 6;
  const int lane = tid & 63;
  const int ln31 = lane & 31;
  const int q = lane >> 5;

  __shared__ uint4 arena16[1280];      // 20 KB; x-stage (main) / reduce zones

  // zero left pad: chunks u in [0,256)
  {
    const int u = tid;
    arena16[((u & 7) * 160) + (u >> 3)] = make_uint4(0, 0, 0, 0);
  }
  // stage x: data chunk u = 256 + u0, u0 in [0,1024)
  {
    const uint4* xg16 = (const uint4*)(xT + (size_t)sid * T);
    for (int u0 = tid; u0 < 1024; u0 += 256) {
      const int u = u0 + 256;
      arena16[((u & 7) * 160) + (u >> 3)] = xg16[u0];
    }
  }
  __syncthreads();

  v16f acc[4][2];
  #pragma unroll
  for (int cc = 0; cc < 4; ++cc)
    #pragma unroll
    for (int rt = 0; rt < 2; ++rt)
      #pragma unroll
      for (int e = 0; e < 16; ++e) acc[cc][rt][e] = 0.f;

  const int s0_par = (8303 - ln31 + 8 * q) & 1;
  const uint* wu = (const uint*)(wr2 + (s0_par ? WREV_COPY_STRIDE : 0) +
                                 (size_t)sid * WREV_LEN);

  for (int K = wave; K < 65; K += 4) {
    const int ibase = -4 + K * 8;
    const int s0 = 8303 - 16 * ibase - ln31 + 8 * q;
    const int dw0 = (s0 - s0_par) >> 1;
    // A fragment ring: av[j] = elements at dwords dw0-8j .. dw0-8j+3
    uint4 av[10];
    #pragma unroll
    for (int j2 = 0; j2 < 10; ++j2)
      av[j2] = ((const U16*)(wu + (dw0 - 8 * j2)))->v;
    #pragma unroll
    for (int ii = 0; ii < 8; ++ii) {
      const int i = ibase + ii;
      const v8bf A0 = __builtin_bit_cast(v8bf, av[ii]);
      const v8bf A1 = __builtin_bit_cast(v8bf, av[ii + 2]);   // dw-16 reuse
      const int m2 = -2 * (i + 1);
      const int u70 = m2 & 7;
      const int u71 = (m2 + 1) & 7;
      const int G0 = u70 * 160 + 32 + ((m2 - u70) >> 3);
      const int G1 = u71 * 160 + 32 + ((m2 + 1 - u71) >> 3);
      const int phi = ln31 + (q ? G1 : G0);
      #pragma unroll
      for (int cc = 0; cc < 4; ++cc) {
        if (i < 128 * (cc + 1)) {
          const uint4 bv = arena16[phi + 32 * cc];
          const v8bf Bf = __builtin_bit_cast(v8bf, bv);
          acc[cc][0] = __builtin_amdgcn_mfma_f32_32x32x16_bf16(A0, Bf, acc[cc][0], 0, 0, 0);
          acc[cc][1] = __builtin_amdgcn_mfma_f32_32x32x16_bf16(A1, Bf, acc[cc][1], 0, 0, 0);
        }
      }
    }
  }

  // ---- cross-wave reduction of partial D tiles through LDS ----
  float* const zbase = (float*)arena16;
  const int rowq = 4 * q;
  #pragma unroll
  for (int cc = 0; cc < 4; ++cc) {
    #pragma unroll
    for (int rt = 0; rt < 2; ++rt) {
      __syncthreads();
      float* zone = zbase + wave * 1152;
      #pragma unroll
      for (int g = 0; g < 4; ++g) {
        float4 v = make_float4(acc[cc][rt][4 * g], acc[cc][rt][4 * g + 1],
                               acc[cc][rt][4 * g + 2], acc[cc][rt][4 * g + 3]);
        *(float4*)(zone + ln31 * 36 + 8 * g + rowq) = v;
      }
      __syncthreads();
      const int n2 = tid & 31, rg = tid >> 5;
      const int zi = n2 * 36 + 4 * rg;
      float4 s0 = *(const float4*)(zbase + 0 * 1152 + zi);
      float4 s1 = *(const float4*)(zbase + 1 * 1152 + zi);
      float4 s2 = *(const float4*)(zbase + 2 * 1152 + zi);
      float4 s3 = *(const float4*)(zbase + 3 * 1152 + zi);
      float4 s;
      s.x = s0.x + s1.x + s2.x + s3.x;
      s.y = s0.y + s1.y + s2.y + s3.y;
      s.z = s0.z + s1.z + s2.z + s3.z;
      s.w = s0.w + s1.w + s2.w + s3.w;
      *(float4*)(yT + (size_t)sid * T + 2048 * cc + 64 * n2 + 32 * rt + 4 * rg) = s;
    }
  }
}

// ---------------- Kernel D: out = Y[:,1:,:] - X[:,:-1,:] @ A^T  (MFMA) ------
// Per block: 64 t-rows x 128 j. Amat (128x128) + X-tile (64x128) staged as
// bf16 in chunk-swizzled LDS. 4 waves, one n-tile each, 2 m-tiles, K=128.
__global__ __launch_bounds__(256) void outk(const float* __restrict__ X,
                                            const float* __restrict__ A,
                                            const float* __restrict__ yT,
                                            float* __restrict__ out) {
  const int b = blockIdx.y;
  const int t0 = blockIdx.x << 6;     // 64 t's per block
  const int tid = threadIdx.x;
  const int wave = tid >> 6;          // = n-tile
  const int lane = tid & 63;
  const int ln31 = lane & 31;
  const int q = lane >> 5;

  __shared__ uint4 arena[3072];       // Amat: 2048 chunks (32KB) + X: 1024 (16KB)

  // stage Amat bf16: chunk (j, c4) at phiA = c4*128 + ((j + c4) & 127)
  {
    const float* Ab = A + (size_t)b * NCH * NCH;
    #pragma unroll
    for (int g = 0; g < 8; ++g) {
      const int u = g * 256 + tid;
      const int jr = u >> 4, c4 = u & 15;
      const float4 f0 = *(const float4*)(Ab + jr * NCH + 8 * c4);
      const float4 f1 = *(const float4*)(Ab + jr * NCH + 8 * c4 + 4);
      uint4 pk;
      pk.x = bf_bits(f0.x) | (bf_bits(f0.y) << 16);
      pk.y = bf_bits(f0.z) | (bf_bits(f0.w) << 16);
      pk.z = bf_bits(f1.x) | (bf_bits(f1.y) << 16);
      pk.w = bf_bits(f1.z) | (bf_bits(f1.w) << 16);
      arena[c4 * 128 + ((jr + c4) & 127)] = pk;
    }
  }
  // stage X-tile bf16: chunk (m, c4) at 2048 + c4*64 + ((m + c4) & 63)
  {
    const float* Xb = X + ((size_t)b * T + t0) * NCH;
    #pragma unroll
    for (int g = 0; g < 4; ++g) {
      const int u = g * 256 + tid;
      const int m = u >> 4, c4 = u & 15;
      const float4 f0 = *(const float4*)(Xb + m * NCH + 8 * c4);
      const float4 f1 = *(const float4*)(Xb + m * NCH + 8 * c4 + 4);
      uint4 pk;
      pk.x = bf_bits(f0.x) | (bf_bits(f0.y) << 16);
      pk.y = bf_bits(f0.z) | (bf_bits(f0.w) << 16);
      pk.z = bf_bits(f1.x) | (bf_bits(f1.y) << 16);
      pk.w = bf_bits(f1.z) | (bf_bits(f1.w) << 16);
      arena[2048 + c4 * 64 + ((m + c4) & 63)] = pk;
    }
  }
  __syncthreads();

  v16f acc[2];
  #pragma unroll
  for (int mt = 0; mt < 2; ++mt)
    #pragma unroll
    for (int e = 0; e < 16; ++e) acc[mt][e] = 0.f;

  const int nt = wave;
  #pragma unroll
  for (int kk = 0; kk < 8; ++kk) {
    const int c4 = 2 * kk + q;
    const uint4 bv = arena[c4 * 128 + ((nt * 32 + ln31 + c4) & 127)];
    const v8bf Bf = __builtin_bit_cast(v8bf, bv);
    #pragma unroll
    for (int mt = 0; mt < 2; ++mt) {
      const uint4 avv = arena[2048 + c4 * 64 + ((mt * 32 + ln31 + c4) & 63)];
      const v8bf Af = __builtin_bit_cast(v8bf, avv);
      acc[mt] = __builtin_amdgcn_mfma_f32_32x32x16_bf16(Af, Bf, acc[mt], 0, 0, 0);
    }
  }

  // epilogue: out[t, j] = yT[j][t+1] - acc ; j = nt*32 + ln31
  const int jj = nt * 32 + ln31;
  const float* yg = yT + ((size_t)(b * NCH + jj)) * T;
  float* og = out + (size_t)b * TM1 * NCH + jj;
  #pragma unroll
  for (int mt = 0; mt < 2; ++mt) {
    #pragma unroll
    for (int g = 0; g < 4; ++g) {
      const int r0 = mt * 32 + 8 * g + 4 * q;          // rows r0..r0+3
      const float4 yv = ((const F16V*)(yg + t0 + r0 + 1))->v;
      #pragma unroll
      for (int e = 0; e < 4; ++e) {
        const int t = t0 + r0 + e;
        const float val = ((const float*)&yv)[e] - acc[mt][4 * g + e];
        if (t < TM1) og[(size_t)t * NCH] = val;
      }
    }
  }
}

extern "C" void kernel_launch(void* const* d_in, const int* in_sizes, int n_in,
                              void* d_out, int out_size, void* d_ws, size_t ws_size,
                              hipStream_t stream) {
  const float* X     = (const float*)d_in[0];   // (8, 8192, 128)
  const float* alpha = (const float*)d_in[1];   // (8, 128)
  const float* A     = (const float*)d_in[2];   // (8, 128, 128)
  float* out = (float*)d_out;                   // (8, 8191, 128)
  char* ws = (char*)d_ws;

  ushort* wr2 = (ushort*)ws;                         // 34,603,008 B
  ushort* xT  = (ushort*)(ws + 34603008);            // 16,777,216 B
  float*  yT  = (float*)(ws + 34603008 + 16777216);  // 33,554,432 B

  hipLaunchKernelGGL(wkern, dim3(NS), dim3(256), 0, stream, alpha, wr2);
  hipLaunchKernelGGL(tkern, dim3(T / 32, NCH / 32, NB), dim3(32, 8), 0, stream, X, xT);
  hipLaunchKernelGGL(convk, dim3(NS), dim3(256), 0, stream, wr2, xT, yT);
  hipLaunchKernelGGL(outk, dim3(T / 64, NB), dim3(256), 0, stream, X, A, yT, out);
}